// Round 14
// baseline (231.378 us; speedup 1.0000x reference)
//
#include <hip/hip_runtime.h>
#include <hip/hip_fp16.h>

// MultiHeadAttention_64106681860559 — round 14: R12 gemm8 schedule (best
// measured) + B-operand direct-to-register (skips LDS for B entirely):
//  - LDS traffic/K-tile 256->160 KB; ds_reads/phase 12->8; LDS 128->64 KB
//  - bfK0/bfK1 single-buffered with one-phase lookahead (WAR-free)
//  - compartment-counted vmcnt(6) (loads pinned between memory-clobber asms)
//
// Workspace (~128 MB):
//   xb fp16 [4096][1024] @0 | wqkvT fp16 [3072][1024] @8M | qkv fp16 [4096][3072] @14M
//   S fp16 [4096][4096] @46M | P fp16 [4096][4096] @78M | vwT fp16 [1024][4096] @118M
//   woutT fp16 [1024][1024] @126M | parts fp16 4x[4096][1024] @14M (qkv+S dead)

typedef _Float16 half_t;
typedef _Float16 half8 __attribute__((ext_vector_type(8)));
typedef _Float16 half4 __attribute__((ext_vector_type(4)));
typedef float f32x4 __attribute__((ext_vector_type(4)));

static constexpr int N_TOK = 4096;
static constexpr int LATENT = 1024;
static constexpr int QKVN = 3072;

#define DEVI __device__ __forceinline__

DEVI void gld_lds16(const half_t* g, half_t* l) {
  __builtin_amdgcn_global_load_lds(
      (const __attribute__((address_space(1))) void*)g,
      (__attribute__((address_space(3))) void*)l,
      16, 0, 0);
}

DEVI f32x4 MFMA(half8 a, half8 b, f32x4 c) {
  return __builtin_amdgcn_mfma_f32_16x16x32_f16(a, b, c, 0, 0, 0);
}

#define BAR() __builtin_amdgcn_s_barrier()
#define PRIO(x) __builtin_amdgcn_s_setprio(x)
#define VMCNT(n) asm volatile("s_waitcnt vmcnt(" #n ")" ::: "memory")

// 64B-row swizzle (R3/R9/R12-proven, 0 conflicts): phys 16B slot p of row r
// holds logical slot p ^ ((r>>1)&3). Stage pre-swizzles source; reads XOR.

// Stage a [256][32] fp16 half-K-tile (1024 x 16B chunks, 512 thr, 2 each).
DEVI void stageH(const half_t* __restrict__ g, int ld, half_t* lbase, int tid) {
#pragma unroll
  for (int i = 0; i < 2; ++i) {
    int c = tid + i * 512;
    int r = c >> 2;
    int k8 = ((c & 3) ^ ((r >> 1) & 3)) * 8;
    gld_lds16(g + (size_t)r * ld + k8, lbase + c * 8);
  }
}

// Load 4 B fragments (one K-half) straight from global: lane reads its own
// 16B at row (colBlk+wc+n*16+fr) — 16 x 64B segments per instruction.
DEVI void loadB(half8 bf[4], const half_t* __restrict__ Blane, int ldb, int koff) {
#pragma unroll
  for (int n = 0; n < 4; ++n)
    bf[n] = *(const half8*)(Blane + (size_t)n * 16 * ldb + koff);
}

// ---------------------------------------------------------------------------
// 256x256 GEMM, 512 thr = 8 waves (2Mx4N), per-wave 128x64 (acc[8][4]).
// BK=64 as two 32-wide K-halves; TWO phases per K-tile:
//   {loadB lookahead | 8 af ds_reads | stage A next | BAR | prio1 | 32 MFMA |
//    prio0 | vmcnt(6) | BAR}
// B never touches LDS. MODE 0: +bias, cols<1024 * 0.125, fp16 (qkv) |
// MODE 1: fp16 (S) | MODE 2: fp16 z-sliced partials (split-K final)
// ---------------------------------------------------------------------------
template <int MODE>
__launch_bounds__(512, 2)
__global__ void gemm8(const half_t* __restrict__ A, int lda,
                      const half_t* __restrict__ B, int ldb,
                      void* __restrict__ Cout, int ldc,
                      const float* __restrict__ bias, int K) {
  __shared__ half_t Alds[2][2][256 * 32];  // [buf][kh] 64 KB total

  const int tid = threadIdx.x;
  const int lane = tid & 63;
  const int wid = tid >> 6;

  // XCD-aware bijective remap (grids are multiples of 8 per z-slice).
  const int nx = gridDim.x;
  const int nwg = nx * gridDim.y;
  const int bid = blockIdx.y * nx + blockIdx.x;
  const int cpx = nwg >> 3;
  const int swz = (bid & 7) * cpx + (bid >> 3);
  const int rowBlk = (swz / nx) * 256;
  const int colBlk = (swz % nx) * 256;

  const int wr = (wid >> 2) * 128;
  const int wc = (wid & 3) * 64;
  const int fr = lane & 15;
  const int fs = lane >> 4;
  const int fs8 = fs * 8;

  const int kOff = blockIdx.z * K;
  const half_t* Ag = A + (size_t)rowBlk * lda + kOff;
  const half_t* Blane = B + (size_t)(colBlk + wc + fr) * ldb + kOff;

  f32x4 acc[8][4] = {};
  half8 af[8], bfK0[4], bfK1[4];
  const int NT = K >> 6;

  // Prologue: tile0 A both halves; tile0 kh0 B frags.
  loadB(bfK0, Blane, ldb, fs8);
  stageH(Ag, lda, Alds[0][0], tid);
  stageH(Ag + 32, lda, Alds[0][1], tid);
  VMCNT(0);
  BAR();

  for (int kt = 0; kt < NT; ++kt) {
    const int b = kt & 1;
    const bool st = (kt + 1 < NT);
    const half_t* AgN = Ag + (kt + 1) * 64;

    // ---- phase kh=0: uses bfK0 (this tile); lookahead-load bfK1 (this tile)
    loadB(bfK1, Blane, ldb, kt * 64 + 32 + fs8);
    {
      const half_t* Ac = Alds[b][0];
#pragma unroll
      for (int m = 0; m < 8; ++m) {
        int row = wr + m * 16 + fr;
        af[m] = *(const half8*)(Ac + row * 32 + ((fs ^ ((row >> 1) & 3)) * 8));
      }
    }
    if (st) stageH(AgN, lda, Alds[b ^ 1][0], tid);
    BAR();
    PRIO(1);
#pragma unroll
    for (int m = 0; m < 8; ++m)
#pragma unroll
      for (int n = 0; n < 4; ++n)
        acc[m][n] = MFMA(af[m], bfK0[n], acc[m][n]);
    PRIO(0);
    if (st) VMCNT(6); else VMCNT(4);
    BAR();

    // ---- phase kh=1: uses bfK1; lookahead-load bfK0 (next tile kh0)
    if (st) loadB(bfK0, Blane, ldb, (kt + 1) * 64 + fs8);
    {
      const half_t* Ac = Alds[b][1];
#pragma unroll
      for (int m = 0; m < 8; ++m) {
        int row = wr + m * 16 + fr;
        af[m] = *(const half8*)(Ac + row * 32 + ((fs ^ ((row >> 1) & 3)) * 8));
      }
    }
    if (st) stageH(AgN + 32, lda, Alds[b ^ 1][1], tid);
    BAR();
    PRIO(1);
#pragma unroll
    for (int m = 0; m < 8; ++m)
#pragma unroll
      for (int n = 0; n < 4; ++n)
        acc[m][n] = MFMA(af[m], bfK1[n], acc[m][n]);
    PRIO(0);
    if (st) VMCNT(6);
    BAR();
  }

  // Epilogue. C/D mapping: col = lane&15, row = (lane>>4)*4 + j.
  const size_t zoff = (MODE == 2) ? (size_t)blockIdx.z * N_TOK * ldc : 0;
#pragma unroll
  for (int m = 0; m < 8; ++m) {
#pragma unroll
    for (int n = 0; n < 4; ++n) {
#pragma unroll
      for (int j = 0; j < 4; ++j) {
        int row = rowBlk + wr + m * 16 + (lane >> 4) * 4 + j;
        int col = colBlk + wc + n * 16 + fr;
        float v = acc[m][n][j];
        if (MODE == 0) {
          v += bias[col];
          if (col < 1024) v *= 0.125f;  // fold 1/sqrt(DK) into q
          ((half_t*)Cout)[(size_t)row * ldc + col] = (half_t)v;
        } else if (MODE == 1) {
          ((half_t*)Cout)[(size_t)row * ldc + col] = (half_t)v;
        } else {
          ((half_t*)Cout)[zoff + (size_t)row * ldc + col] = (half_t)v;
        }
      }
    }
  }
}

// ---------------------------------------------------------------------------
// 2-phase 128x128 GEMM — small vwT GEMM only (unchanged from R12).
// ---------------------------------------------------------------------------
template <int ROWS>
DEVI void stage32(const half_t* __restrict__ g, int ld, half_t* lbase, int tid) {
#pragma unroll
  for (int c = tid; c < ROWS * 4; c += 256) {
    int r = c >> 2;
    int k8 = ((c & 3) ^ ((r >> 1) & 3)) * 8;
    gld_lds16(g + (size_t)r * ld + k8, lbase + c * 8);
  }
}

__launch_bounds__(256, 2)
__global__ void gemm2(const half_t* __restrict__ A, int lda,
                      const half_t* __restrict__ B, int ldb,
                      half_t* __restrict__ Cout, int ldc, int K) {
  constexpr int BM = 128, BN = 128, MF = 4, NF = 4;
  __shared__ half_t At[2][BM * 32];
  __shared__ half_t Bt[2][BN * 32];

  const int tid = threadIdx.x;
  const int lane = tid & 63;
  const int wid = tid >> 6;

  const int nx = gridDim.x;
  const int nwg = nx * gridDim.y;
  const int bid = blockIdx.y * nx + blockIdx.x;
  const int cpx = nwg >> 3;
  const int swz = (bid & 7) * cpx + (bid >> 3);
  const int rowBlk = (swz / nx) * BM;
  const int colBlk = (swz % nx) * BN;

  const int wr = (wid >> 1) * (BM / 2);
  const int wc = (wid & 1) * (BN / 2);
  const int fr = lane & 15;
  const int fs = lane >> 4;

  const half_t* Ag = A + (size_t)rowBlk * lda;
  const half_t* Bg = B + (size_t)colBlk * ldb;

  f32x4 acc[MF][NF] = {};
  const int NT = K >> 5;
  stage32<BM>(Ag, lda, At[0], tid);
  stage32<BN>(Bg, ldb, Bt[0], tid);
  __syncthreads();

  int cur = 0;
  for (int t = 0; t < NT; ++t) {
    if (t + 1 < NT) {
      stage32<BM>(Ag + (t + 1) * 32, lda, At[cur ^ 1], tid);
      stage32<BN>(Bg + (t + 1) * 32, ldb, Bt[cur ^ 1], tid);
    }
    const half_t* Ac = At[cur];
    const half_t* Bc = Bt[cur];
    half8 af[MF], bf[NF];
#pragma unroll
    for (int m = 0; m < MF; ++m) {
      int row = wr + m * 16 + fr;
      af[m] = *(const half8*)(Ac + row * 32 + ((fs ^ ((row >> 1) & 3)) * 8));
    }
#pragma unroll
    for (int n = 0; n < NF; ++n) {
      int row = wc + n * 16 + fr;
      bf[n] = *(const half8*)(Bc + row * 32 + ((fs ^ ((row >> 1) & 3)) * 8));
    }
#pragma unroll
    for (int m = 0; m < MF; ++m)
#pragma unroll
      for (int n = 0; n < NF; ++n)
        acc[m][n] = MFMA(af[m], bf[n], acc[m][n]);
    __syncthreads();
    cur ^= 1;
  }

#pragma unroll
  for (int m = 0; m < MF; ++m)
#pragma unroll
    for (int n = 0; n < NF; ++n)
#pragma unroll
      for (int j = 0; j < 4; ++j) {
        int row = rowBlk + wr + m * 16 + (lane >> 4) * 4 + j;
        int col = colBlk + wc + n * 16 + fr;
        Cout[(size_t)row * ldc + col] = (half_t)acc[m][n][j];
      }
}

// ---------------------------------------------------------------------------
// Split-K reduce: out = sum of 4 fp16 partials + bias (f32 out).
// ---------------------------------------------------------------------------
__launch_bounds__(256)
__global__ void reduce_bias4(const half_t* __restrict__ p, const float* __restrict__ bias,
                             float* __restrict__ out) {
  int i = blockIdx.x * 256 + threadIdx.x;  // half8 index
  const size_t stride8 = (size_t)N_TOK * LATENT / 8;
  half8 a = ((const half8*)p)[i];
  half8 b = ((const half8*)p)[i + stride8];
  half8 c = ((const half8*)p)[i + 2 * stride8];
  half8 d = ((const half8*)p)[i + 3 * stride8];
  float4 e0 = ((const float4*)bias)[(i & 127) * 2];
  float4 e1 = ((const float4*)bias)[(i & 127) * 2 + 1];
  float r[8];
#pragma unroll
  for (int j = 0; j < 8; ++j)
    r[j] = (float)a[j] + (float)b[j] + (float)c[j] + (float)d[j];
  float4 o0, o1;
  o0.x = r[0] + e0.x; o0.y = r[1] + e0.y; o0.z = r[2] + e0.z; o0.w = r[3] + e0.w;
  o1.x = r[4] + e1.x; o1.y = r[5] + e1.y; o1.z = r[6] + e1.z; o1.w = r[7] + e1.w;
  ((float4*)out)[i * 2] = o0;
  ((float4*)out)[i * 2 + 1] = o1;
}

// ---------------------------------------------------------------------------
// Row softmax: S fp16 [4096][4096] -> P fp16. One block (256 thr) per row.
// ---------------------------------------------------------------------------
__launch_bounds__(256)
__global__ void softmax_rows(const half_t* __restrict__ S, half_t* __restrict__ P) {
  const int row = blockIdx.x;
  const int t = threadIdx.x;
  const half8* s8 = (const half8*)(S + (size_t)row * N_TOK);

  half8 v[2];
  float lmax = -1e30f;
#pragma unroll
  for (int i = 0; i < 2; ++i) {
    v[i] = s8[t + i * 256];
#pragma unroll
    for (int j = 0; j < 8; ++j) lmax = fmaxf(lmax, (float)v[i][j]);
  }
#pragma unroll
  for (int off = 32; off; off >>= 1) lmax = fmaxf(lmax, __shfl_xor(lmax, off));

  __shared__ float redm[4];
  __shared__ float reds[4];
  if ((t & 63) == 0) redm[t >> 6] = lmax;
  __syncthreads();
  lmax = fmaxf(fmaxf(redm[0], redm[1]), fmaxf(redm[2], redm[3]));

  float e[16];
  float lsum = 0.f;
#pragma unroll
  for (int i = 0; i < 2; ++i)
#pragma unroll
    for (int j = 0; j < 8; ++j) {
      float ev = __expf((float)v[i][j] - lmax);
      e[i * 8 + j] = ev;
      lsum += ev;
    }
#pragma unroll
  for (int off = 32; off; off >>= 1) lsum += __shfl_xor(lsum, off);
  if ((t & 63) == 0) reds[t >> 6] = lsum;
  __syncthreads();
  float inv = 1.f / (reds[0] + reds[1] + reds[2] + reds[3]);

  half8* p8 = (half8*)(P + (size_t)row * N_TOK);
#pragma unroll
  for (int i = 0; i < 2; ++i) {
    half8 h;
#pragma unroll
    for (int j = 0; j < 8; ++j) h[j] = (half_t)(e[i * 8 + j] * inv);
    p8[t + i * 256] = h;
  }
}

// ---------------------------------------------------------------------------
// Transpose [R][C] -> fp16 [C][R].
// ---------------------------------------------------------------------------
template <typename TI>
__global__ void transpose_to_f16(const TI* __restrict__ in, int ldin,
                                 half_t* __restrict__ out, int ldout) {
  __shared__ float tile[32][33];
  const int cb = blockIdx.x * 32;
  const int rb = blockIdx.y * 32;
  const int tx = threadIdx.x;
#pragma unroll
  for (int i = threadIdx.y; i < 32; i += 8)
    tile[i][tx] = (float)in[(size_t)(rb + i) * ldin + cb + tx];
  __syncthreads();
#pragma unroll
  for (int i = threadIdx.y; i < 32; i += 8)
    out[(size_t)(cb + i) * ldout + rb + tx] = (half_t)tile[tx][i];
}

__global__ void cvt_f32_f16(const float* __restrict__ in, half_t* __restrict__ out) {
  int i = blockIdx.x * 256 + threadIdx.x;
  float4 v = ((const float4*)in)[i];
  half4 h;
  h[0] = (half_t)v.x; h[1] = (half_t)v.y; h[2] = (half_t)v.z; h[3] = (half_t)v.w;
  ((half4*)out)[i] = h;
}

extern "C" void kernel_launch(void* const* d_in, const int* in_sizes, int n_in,
                              void* d_out, int out_size, void* d_ws, size_t ws_size,
                              hipStream_t stream) {
  const float* x = (const float*)d_in[0];
  const float* w_qkv = (const float*)d_in[1];
  const float* b_qkv = (const float*)d_in[2];
  const float* w_out = (const float*)d_in[3];
  const float* b_out = (const float*)d_in[4];
  float* out = (float*)d_out;

  char* ws = (char*)d_ws;
  half_t* xb    = (half_t*)(ws);
  half_t* wqkvT = (half_t*)(ws + ((size_t)8 << 20));
  half_t* qkv   = (half_t*)(ws + ((size_t)14 << 20));
  half_t* S     = (half_t*)(ws + ((size_t)46 << 20));
  half_t* P     = (half_t*)(ws + ((size_t)78 << 20));
  half_t* vwT   = (half_t*)(ws + ((size_t)118 << 20));
  half_t* woutT = (half_t*)(ws + ((size_t)126 << 20));
  half_t* parts = (half_t*)(ws + ((size_t)14 << 20));  // qkv+S dead by then

  dim3 tb(32, 8);

  // 1. x -> fp16
  cvt_f32_f16<<<(N_TOK * LATENT) / (256 * 4), 256, 0, stream>>>(x, xb);
  // 2. w_qkv -> wqkvT [3072][1024] fp16
  transpose_to_f16<float><<<dim3(QKVN / 32, LATENT / 32), tb, 0, stream>>>(w_qkv, QKVN, wqkvT, LATENT);
  // 3. w_out -> woutT [1024][1024] fp16
  transpose_to_f16<float><<<dim3(LATENT / 32, LATENT / 32), tb, 0, stream>>>(w_out, LATENT, woutT, LATENT);
  // 4. qkv = x @ w_qkv + b (q scaled 0.125)  (192 blocks @ 256x256)
  gemm8<0><<<dim3(QKVN / 256, N_TOK / 256), 512, 0, stream>>>(
      xb, LATENT, wqkvT, LATENT, qkv, QKVN, b_qkv, LATENT);
  // 5. vwT[j][t] = sum_c woutT[j][c] * v[t][c]  (256 blocks @ 128x128)
  gemm2<<<dim3(N_TOK / 128, LATENT / 128), 256, 0, stream>>>(
      woutT, LATENT, qkv + 2 * LATENT, QKVN, vwT, N_TOK, LATENT);
  // 6. S = q' @ k^T  (256 blocks @ 256x256)
  gemm8<1><<<dim3(N_TOK / 256, N_TOK / 256), 512, 0, stream>>>(
      qkv, QKVN, qkv + LATENT, QKVN, S, N_TOK, nullptr, LATENT);
  // 7. P = softmax rows
  softmax_rows<<<N_TOK, 256, 0, stream>>>(S, P);
  // 8. parts = P @ vwT, split-K=4, fp16 partials  (4 x 64 blocks @ 256x256)
  gemm8<2><<<dim3(LATENT / 256, N_TOK / 256, 4), 512, 0, stream>>>(
      P, N_TOK, vwT, N_TOK, parts, LATENT, nullptr, 1024);
  // 9. out = sum(parts) + b_out
  reduce_bias4<<<(N_TOK * LATENT) / (256 * 8), 256, 0, stream>>>(parts, b_out, out);
}

// Round 16
// 175.053 us; speedup vs baseline: 1.3218x; 1.3218x over previous
//
#include <hip/hip_runtime.h>
#include <hip/hip_fp16.h>

// MultiHeadAttention_64106681860559 — round 16: R12 base (fp16 everywhere,
// i8 reverted) + 3-buffer 2-phase-deep staging pipeline (BK=32, 96 KB LDS):
// stage tile t+2 during phase t; vmcnt(4) -> every stage has ~2 phases to land.
//
// Workspace (~128 MB):
//   xb fp16 [4096][1024] @0 | wqkvT fp16 [3072][1024] @8M | qkv fp16 [4096][3072] @14M
//   S fp16 [4096][4096] @46M | P fp16 [4096][4096] @78M | vwT fp16 [1024][4096] @118M
//   woutT fp16 [1024][1024] @126M | parts fp16 4x[4096][1024] @14M (qkv+S dead)

typedef _Float16 half_t;
typedef _Float16 half8 __attribute__((ext_vector_type(8)));
typedef _Float16 half4 __attribute__((ext_vector_type(4)));
typedef float f32x4 __attribute__((ext_vector_type(4)));

static constexpr int N_TOK = 4096;
static constexpr int LATENT = 1024;
static constexpr int QKVN = 3072;

#define DEVI __device__ __forceinline__
#define BAR() __builtin_amdgcn_s_barrier()
#define PRIO(x) __builtin_amdgcn_s_setprio(x)
#define VMCNT(n) asm volatile("s_waitcnt vmcnt(" #n ")" ::: "memory")

DEVI void gld_lds16(const half_t* g, half_t* l) {
  __builtin_amdgcn_global_load_lds(
      (const __attribute__((address_space(1))) void*)g,
      (__attribute__((address_space(3))) void*)l,
      16, 0, 0);
}

DEVI f32x4 MFMA(half8 a, half8 b, f32x4 c) {
  return __builtin_amdgcn_mfma_f32_16x16x32_f16(a, b, c, 0, 0, 0);
}

// ---- 64B-row swizzle (0 conflicts, R3/R9/R12-proven): phys 16B slot p of row
// r holds logical slot p ^ ((r>>1)&3). Pre-swizzled source; XOR on read.

// Stage one [256][32] fp16 K-tile of A AND B (2048 chunks, 512 thr, 4 ops).
DEVI void stageAB(const half_t* __restrict__ ga, int lda,
                  const half_t* __restrict__ gb, int ldb,
                  half_t* la, half_t* lb, int tid) {
#pragma unroll
  for (int i = 0; i < 2; ++i) {
    int c = tid + i * 512;
    int r = c >> 2;
    int k8 = ((c & 3) ^ ((r >> 1) & 3)) * 8;
    gld_lds16(ga + (size_t)r * lda + k8, la + c * 8);
    gld_lds16(gb + (size_t)r * ldb + k8, lb + c * 8);
  }
}

// ---------------------------------------------------------------------------
// 256x256 GEMM, 512 thr = 8 waves (2Mx4N), per-wave 128x64 (acc[8][4]).
// BK=32 tiles through 3 LDS buffers; per phase:
//   {12 ds_reads buf[t%3] | stage tile t+2 -> buf[(t+2)%3] | BAR | prio1 |
//    32 MFMA | prio0 | vmcnt(4) | BAR}
// MODE 0: +bias, cols<1024 * 0.125, fp16 (qkv) | MODE 1: fp16 (S) |
// MODE 2: fp16 z-sliced partials (split-K final)
// ---------------------------------------------------------------------------
template <int MODE>
__launch_bounds__(512, 2)
__global__ void gemm8h(const half_t* __restrict__ A, int lda,
                       const half_t* __restrict__ B, int ldb,
                       void* __restrict__ Cout, int ldc,
                       const float* __restrict__ bias, int K) {
  __shared__ half_t Alds[3][256 * 32];  // 48 KB
  __shared__ half_t Blds[3][256 * 32];  // 48 KB

  const int tid = threadIdx.x;
  const int lane = tid & 63;
  const int wid = tid >> 6;

  // XCD-aware bijective remap (grids are multiples of 8 per z-slice).
  const int nx = gridDim.x;
  const int nwg = nx * gridDim.y;
  const int bid = blockIdx.y * nx + blockIdx.x;
  const int cpx = nwg >> 3;
  const int swz = (bid & 7) * cpx + (bid >> 3);
  const int rowBlk = (swz / nx) * 256;
  const int colBlk = (swz % nx) * 256;

  const int wr = (wid >> 2) * 128;
  const int wc = (wid & 3) * 64;
  const int fr = lane & 15;
  const int fs = lane >> 4;

  const int kOff = blockIdx.z * K;
  const half_t* Ag = A + (size_t)rowBlk * lda + kOff;
  const half_t* Bg = B + (size_t)colBlk * ldb + kOff;

  f32x4 acc[8][4] = {};
  const int NT = K >> 5;  // 32-wide K-tiles

  // Prologue: stage tiles 0 (buf0) and 1 (buf1); wait tile 0 (leave 1 flying).
  stageAB(Ag, lda, Bg, ldb, Alds[0], Blds[0], tid);
  stageAB(Ag + 32, lda, Bg + 32, ldb, Alds[1], Blds[1], tid);
  VMCNT(4);
  BAR();

  for (int t = 0; t < NT; ++t) {
    const int b = t % 3;
    const half_t* Ac = Alds[b];
    const half_t* Bc = Blds[b];

    half8 af[8], bf[4];
#pragma unroll
    for (int m = 0; m < 8; ++m) {
      int row = wr + m * 16 + fr;
      af[m] = *(const half8*)(Ac + row * 32 + ((fs ^ ((row >> 1) & 3)) * 8));
    }
#pragma unroll
    for (int n = 0; n < 4; ++n) {
      int row = wc + n * 16 + fr;
      bf[n] = *(const half8*)(Bc + row * 32 + ((fs ^ ((row >> 1) & 3)) * 8));
    }
    // stage tile t+2 into buf[(t+2)%3] (WAR-safe: last read at phase t-1)
    if (t + 2 < NT) {
      const int b2 = (t + 2) % 3;
      stageAB(Ag + (t + 2) * 32, lda, Bg + (t + 2) * 32, ldb,
              Alds[b2], Blds[b2], tid);
    }
    BAR();
    PRIO(1);
#pragma unroll
    for (int m = 0; m < 8; ++m)
#pragma unroll
      for (int n = 0; n < 4; ++n)
        acc[m][n] = MFMA(af[m], bf[n], acc[m][n]);
    PRIO(0);
    // Leave only the newest 4 ops (tile t+2's) in flight -> tile t+1 landed.
    if (t + 2 < NT) VMCNT(4);
    else if (t + 1 < NT) VMCNT(0);
    BAR();
  }

  // Epilogue. C/D mapping: col = lane&15, row = (lane>>4)*4 + j.
  const size_t zoff = (MODE == 2) ? (size_t)blockIdx.z * N_TOK * ldc : 0;
#pragma unroll
  for (int m = 0; m < 8; ++m) {
#pragma unroll
    for (int n = 0; n < 4; ++n) {
#pragma unroll
      for (int j = 0; j < 4; ++j) {
        int row = rowBlk + wr + m * 16 + (lane >> 4) * 4 + j;
        int col = colBlk + wc + n * 16 + fr;
        float v = acc[m][n][j];
        if (MODE == 0) {
          v += bias[col];
          if (col < 1024) v *= 0.125f;  // fold 1/sqrt(DK) into q
          ((half_t*)Cout)[(size_t)row * ldc + col] = (half_t)v;
        } else if (MODE == 1) {
          ((half_t*)Cout)[(size_t)row * ldc + col] = (half_t)v;
        } else {
          ((half_t*)Cout)[zoff + (size_t)row * ldc + col] = (half_t)v;
        }
      }
    }
  }
}

// ---------------------------------------------------------------------------
// 2-phase 128x128 GEMM — small vwT GEMM only (unchanged).
// ---------------------------------------------------------------------------
template <int ROWS>
DEVI void stage32(const half_t* __restrict__ g, int ld, half_t* lbase, int tid) {
#pragma unroll
  for (int c = tid; c < ROWS * 4; c += 256) {
    int r = c >> 2;
    int k8 = ((c & 3) ^ ((r >> 1) & 3)) * 8;
    gld_lds16(g + (size_t)r * ld + k8, lbase + c * 8);
  }
}

__launch_bounds__(256, 2)
__global__ void gemm2(const half_t* __restrict__ A, int lda,
                      const half_t* __restrict__ B, int ldb,
                      half_t* __restrict__ Cout, int ldc, int K) {
  constexpr int BM = 128, BN = 128, MF = 4, NF = 4;
  __shared__ half_t At[2][BM * 32];
  __shared__ half_t Bt[2][BN * 32];

  const int tid = threadIdx.x;
  const int lane = tid & 63;
  const int wid = tid >> 6;

  const int nx = gridDim.x;
  const int nwg = nx * gridDim.y;
  const int bid = blockIdx.y * nx + blockIdx.x;
  const int cpx = nwg >> 3;
  const int swz = (bid & 7) * cpx + (bid >> 3);
  const int rowBlk = (swz / nx) * BM;
  const int colBlk = (swz % nx) * BN;

  const int wr = (wid >> 1) * (BM / 2);
  const int wc = (wid & 1) * (BN / 2);
  const int fr = lane & 15;
  const int fs = lane >> 4;

  const half_t* Ag = A + (size_t)rowBlk * lda;
  const half_t* Bg = B + (size_t)colBlk * ldb;

  f32x4 acc[MF][NF] = {};
  const int NT = K >> 5;
  stage32<BM>(Ag, lda, At[0], tid);
  stage32<BN>(Bg, ldb, Bt[0], tid);
  __syncthreads();

  int cur = 0;
  for (int t = 0; t < NT; ++t) {
    if (t + 1 < NT) {
      stage32<BM>(Ag + (t + 1) * 32, lda, At[cur ^ 1], tid);
      stage32<BN>(Bg + (t + 1) * 32, ldb, Bt[cur ^ 1], tid);
    }
    const half_t* Ac = At[cur];
    const half_t* Bc = Bt[cur];
    half8 af[MF], bf[NF];
#pragma unroll
    for (int m = 0; m < MF; ++m) {
      int row = wr + m * 16 + fr;
      af[m] = *(const half8*)(Ac + row * 32 + ((fs ^ ((row >> 1) & 3)) * 8));
    }
#pragma unroll
    for (int n = 0; n < NF; ++n) {
      int row = wc + n * 16 + fr;
      bf[n] = *(const half8*)(Bc + row * 32 + ((fs ^ ((row >> 1) & 3)) * 8));
    }
#pragma unroll
    for (int m = 0; m < MF; ++m)
#pragma unroll
      for (int n = 0; n < NF; ++n)
        acc[m][n] = MFMA(af[m], bf[n], acc[m][n]);
    __syncthreads();
    cur ^= 1;
  }

#pragma unroll
  for (int m = 0; m < MF; ++m)
#pragma unroll
    for (int n = 0; n < NF; ++n)
#pragma unroll
      for (int j = 0; j < 4; ++j) {
        int row = rowBlk + wr + m * 16 + (lane >> 4) * 4 + j;
        int col = colBlk + wc + n * 16 + fr;
        Cout[(size_t)row * ldc + col] = (half_t)acc[m][n][j];
      }
}

// ---------------------------------------------------------------------------
// Split-K reduce: out = sum of 4 fp16 partials + bias (f32 out).
// ---------------------------------------------------------------------------
__launch_bounds__(256)
__global__ void reduce_bias4(const half_t* __restrict__ p, const float* __restrict__ bias,
                             float* __restrict__ out) {
  int i = blockIdx.x * 256 + threadIdx.x;  // half8 index
  const size_t stride8 = (size_t)N_TOK * LATENT / 8;
  half8 a = ((const half8*)p)[i];
  half8 b = ((const half8*)p)[i + stride8];
  half8 c = ((const half8*)p)[i + 2 * stride8];
  half8 d = ((const half8*)p)[i + 3 * stride8];
  float4 e0 = ((const float4*)bias)[(i & 127) * 2];
  float4 e1 = ((const float4*)bias)[(i & 127) * 2 + 1];
  float r[8];
#pragma unroll
  for (int j = 0; j < 8; ++j)
    r[j] = (float)a[j] + (float)b[j] + (float)c[j] + (float)d[j];
  float4 o0, o1;
  o0.x = r[0] + e0.x; o0.y = r[1] + e0.y; o0.z = r[2] + e0.z; o0.w = r[3] + e0.w;
  o1.x = r[4] + e1.x; o1.y = r[5] + e1.y; o1.z = r[6] + e1.z; o1.w = r[7] + e1.w;
  ((float4*)out)[i * 2] = o0;
  ((float4*)out)[i * 2 + 1] = o1;
}

// ---------------------------------------------------------------------------
// Row softmax: S fp16 [4096][4096] -> P fp16. One block (256 thr) per row.
// ---------------------------------------------------------------------------
__launch_bounds__(256)
__global__ void softmax_rows(const half_t* __restrict__ S, half_t* __restrict__ P) {
  const int row = blockIdx.x;
  const int t = threadIdx.x;
  const half8* s8 = (const half8*)(S + (size_t)row * N_TOK);

  half8 v[2];
  float lmax = -1e30f;
#pragma unroll
  for (int i = 0; i < 2; ++i) {
    v[i] = s8[t + i * 256];
#pragma unroll
    for (int j = 0; j < 8; ++j) lmax = fmaxf(lmax, (float)v[i][j]);
  }
#pragma unroll
  for (int off = 32; off; off >>= 1) lmax = fmaxf(lmax, __shfl_xor(lmax, off));

  __shared__ float redm[4];
  __shared__ float reds[4];
  if ((t & 63) == 0) redm[t >> 6] = lmax;
  __syncthreads();
  lmax = fmaxf(fmaxf(redm[0], redm[1]), fmaxf(redm[2], redm[3]));

  float e[16];
  float lsum = 0.f;
#pragma unroll
  for (int i = 0; i < 2; ++i)
#pragma unroll
    for (int j = 0; j < 8; ++j) {
      float ev = __expf((float)v[i][j] - lmax);
      e[i * 8 + j] = ev;
      lsum += ev;
    }
#pragma unroll
  for (int off = 32; off; off >>= 1) lsum += __shfl_xor(lsum, off);
  if ((t & 63) == 0) reds[t >> 6] = lsum;
  __syncthreads();
  float inv = 1.f / (reds[0] + reds[1] + reds[2] + reds[3]);

  half8* p8 = (half8*)(P + (size_t)row * N_TOK);
#pragma unroll
  for (int i = 0; i < 2; ++i) {
    half8 h;
#pragma unroll
    for (int j = 0; j < 8; ++j) h[j] = (half_t)(e[i * 8 + j] * inv);
    p8[t + i * 256] = h;
  }
}

// ---------------------------------------------------------------------------
// Transpose [R][C] -> fp16 [C][R].
// ---------------------------------------------------------------------------
template <typename TI>
__global__ void transpose_to_f16(const TI* __restrict__ in, int ldin,
                                 half_t* __restrict__ out, int ldout) {
  __shared__ float tile[32][33];
  const int cb = blockIdx.x * 32;
  const int rb = blockIdx.y * 32;
  const int tx = threadIdx.x;
#pragma unroll
  for (int i = threadIdx.y; i < 32; i += 8)
    tile[i][tx] = (float)in[(size_t)(rb + i) * ldin + cb + tx];
  __syncthreads();
#pragma unroll
  for (int i = threadIdx.y; i < 32; i += 8)
    out[(size_t)(cb + i) * ldout + rb + tx] = (half_t)tile[tx][i];
}

__global__ void cvt_f32_f16(const float* __restrict__ in, half_t* __restrict__ out) {
  int i = blockIdx.x * 256 + threadIdx.x;
  float4 v = ((const float4*)in)[i];
  half4 h;
  h[0] = (half_t)v.x; h[1] = (half_t)v.y; h[2] = (half_t)v.z; h[3] = (half_t)v.w;
  ((half4*)out)[i] = h;
}

extern "C" void kernel_launch(void* const* d_in, const int* in_sizes, int n_in,
                              void* d_out, int out_size, void* d_ws, size_t ws_size,
                              hipStream_t stream) {
  const float* x = (const float*)d_in[0];
  const float* w_qkv = (const float*)d_in[1];
  const float* b_qkv = (const float*)d_in[2];
  const float* w_out = (const float*)d_in[3];
  const float* b_out = (const float*)d_in[4];
  float* out = (float*)d_out;

  char* ws = (char*)d_ws;
  half_t* xb    = (half_t*)(ws);
  half_t* wqkvT = (half_t*)(ws + ((size_t)8 << 20));
  half_t* qkv   = (half_t*)(ws + ((size_t)14 << 20));
  half_t* S     = (half_t*)(ws + ((size_t)46 << 20));
  half_t* P     = (half_t*)(ws + ((size_t)78 << 20));
  half_t* vwT   = (half_t*)(ws + ((size_t)118 << 20));
  half_t* woutT = (half_t*)(ws + ((size_t)126 << 20));
  half_t* parts = (half_t*)(ws + ((size_t)14 << 20));  // qkv+S dead by then

  dim3 tb(32, 8);

  // 1. x -> fp16
  cvt_f32_f16<<<(N_TOK * LATENT) / (256 * 4), 256, 0, stream>>>(x, xb);
  // 2. w_qkv -> wqkvT [3072][1024] fp16
  transpose_to_f16<float><<<dim3(QKVN / 32, LATENT / 32), tb, 0, stream>>>(w_qkv, QKVN, wqkvT, LATENT);
  // 3. w_out -> woutT [1024][1024] fp16
  transpose_to_f16<float><<<dim3(LATENT / 32, LATENT / 32), tb, 0, stream>>>(w_out, LATENT, woutT, LATENT);
  // 4. qkv = x @ w_qkv + b (q scaled 0.125)  (192 blocks @ 256x256)
  gemm8h<0><<<dim3(QKVN / 256, N_TOK / 256), 512, 0, stream>>>(
      xb, LATENT, wqkvT, LATENT, qkv, QKVN, b_qkv, LATENT);
  // 5. vwT[j][t] = sum_c woutT[j][c] * v[t][c]  (256 blocks @ 128x128)
  gemm2<<<dim3(N_TOK / 128, LATENT / 128), 256, 0, stream>>>(
      woutT, LATENT, qkv + 2 * LATENT, QKVN, vwT, N_TOK, LATENT);
  // 6. S = q' @ k^T  (256 blocks @ 256x256)
  gemm8h<1><<<dim3(N_TOK / 256, N_TOK / 256), 512, 0, stream>>>(
      qkv, QKVN, qkv + LATENT, QKVN, S, N_TOK, nullptr, LATENT);
  // 7. P = softmax rows
  softmax_rows<<<N_TOK, 256, 0, stream>>>(S, P);
  // 8. parts = P @ vwT, split-K=4, fp16 partials  (4 x 64 blocks @ 256x256)
  gemm8h<2><<<dim3(LATENT / 256, N_TOK / 256, 4), 512, 0, stream>>>(
      P, N_TOK, vwT, N_TOK, parts, LATENT, nullptr, 1024);
  // 9. out = sum(parts) + b_out
  reduce_bias4<<<(N_TOK * LATENT) / (256 * 8), 256, 0, stream>>>(parts, b_out, out);
}